// Round 1
// baseline (530.071 us; speedup 1.0000x reference)
//
#include <hip/hip_runtime.h>

#define N_NODES 100000
#define DIM     128
#define NEDGE   640000
#define BN_EPS  1e-5f
#define BM      32      // rows per GEMM block
#define BK      64      // k-slice per phase (keeps LDS at 40KB)

// ---------------------------------------------------------------------------
// Scatter-add: agg[dst] += x[src], one thread per (edge, feature).
// x row reads are fully coalesced (128 consecutive floats per edge).
__global__ __launch_bounds__(256) void k_scatter(const float* __restrict__ x,
                                                 const int* __restrict__ ei,
                                                 float* __restrict__ agg) {
    int idx = blockIdx.x * 256 + threadIdx.x;   // < 81,920,000, fits int
    int e = idx >> 7;
    int f = idx & 127;
    if (e < NEDGE) {
        int src = ei[e];
        int dst = ei[NEDGE + e];
        atomicAdd(&agg[(size_t)dst * DIM + f], x[(size_t)src * DIM + f]);
    }
}

// ---------------------------------------------------------------------------
// GEMM1: h = (agg + (1+eps)*x) @ W1 + b1, plus per-column sum/sumsq stats.
// Block: 256 threads, 32 rows x 128 cols, each thread 4x4 outputs.
__global__ __launch_bounds__(256) void k_gemm1(const float* __restrict__ agg,
                                               const float* __restrict__ x,
                                               const float* __restrict__ epsp,
                                               const float* __restrict__ W1,
                                               const float* __restrict__ b1,
                                               float* __restrict__ h,
                                               float* __restrict__ stats) {
    __shared__ float Bs[BK * DIM];   // 32 KB: W1 k-slice, [k][c]
    __shared__ float As[BM * BK];    // 8 KB:  A tile,     [r][k]
    const int t = threadIdx.x;
    const int row0 = blockIdx.x * BM;
    const float scale = 1.0f + epsp[0];
    const int trow = (t >> 5) * 4;   // 0..28
    const int tcol = (t & 31) * 4;   // 0..124

    float acc[4][4];
    #pragma unroll
    for (int i = 0; i < 4; ++i)
        #pragma unroll
        for (int j = 0; j < 4; ++j)
            acc[i][j] = b1[tcol + j];

    for (int k0 = 0; k0 < DIM; k0 += BK) {
        const float* wsrc = W1 + k0 * DIM;       // contiguous BK*DIM block
        #pragma unroll
        for (int i = t * 4; i < BK * DIM; i += 256 * 4)
            *(float4*)&Bs[i] = *(const float4*)&wsrc[i];
        #pragma unroll
        for (int i = t * 4; i < BM * BK; i += 256 * 4) {
            int r = i >> 6;            // / BK
            int c = i & (BK - 1);
            size_t g = (size_t)(row0 + r) * DIM + k0 + c;
            float4 av = *(const float4*)&agg[g];
            float4 xv = *(const float4*)&x[g];
            av.x = fmaf(scale, xv.x, av.x);
            av.y = fmaf(scale, xv.y, av.y);
            av.z = fmaf(scale, xv.z, av.z);
            av.w = fmaf(scale, xv.w, av.w);
            *(float4*)&As[i] = av;
        }
        __syncthreads();
        #pragma unroll
        for (int kk = 0; kk < BK; kk += 4) {
            float4 a4[4];
            #pragma unroll
            for (int i = 0; i < 4; ++i)
                a4[i] = *(const float4*)&As[(trow + i) * BK + kk];
            #pragma unroll
            for (int j4 = 0; j4 < 4; ++j4) {
                float4 b = *(const float4*)&Bs[(kk + j4) * DIM + tcol];
                #pragma unroll
                for (int i = 0; i < 4; ++i) {
                    float av = ((const float*)&a4[i])[j4];
                    acc[i][0] = fmaf(av, b.x, acc[i][0]);
                    acc[i][1] = fmaf(av, b.y, acc[i][1]);
                    acc[i][2] = fmaf(av, b.z, acc[i][2]);
                    acc[i][3] = fmaf(av, b.w, acc[i][3]);
                }
            }
        }
        __syncthreads();
    }

    #pragma unroll
    for (int i = 0; i < 4; ++i) {
        float4 v = make_float4(acc[i][0], acc[i][1], acc[i][2], acc[i][3]);
        *(float4*)&h[(size_t)(row0 + trow + i) * DIM + tcol] = v;
    }

    // Per-column partial sums over this block's 32 rows -> LDS -> 2 atomics/col.
    float s[4], q[4];
    #pragma unroll
    for (int j = 0; j < 4; ++j) {
        s[j] = acc[0][j] + acc[1][j] + acc[2][j] + acc[3][j];
        q[j] = acc[0][j] * acc[0][j] + acc[1][j] * acc[1][j] +
               acc[2][j] * acc[2][j] + acc[3][j] * acc[3][j];
    }
    int rg = t >> 5;  // 0..7
    #pragma unroll
    for (int j = 0; j < 4; ++j) {
        As[rg * 128 + tcol + j] = s[j];          // 1024 floats
        As[1024 + rg * 128 + tcol + j] = q[j];   // 1024 floats (As = 2048 total)
    }
    __syncthreads();
    if (t < 128) {
        float ss = 0.f, qq = 0.f;
        #pragma unroll
        for (int g = 0; g < 8; ++g) {
            ss += As[g * 128 + t];
            qq += As[1024 + g * 128 + t];
        }
        atomicAdd(&stats[t], ss);
        atomicAdd(&stats[DIM + t], qq);
    }
}

// ---------------------------------------------------------------------------
// Finalize BN: stats[256+c] = a = gamma*rsqrt(var+eps); stats[384+c] = beta - mu*a
__global__ void k_finalize(const float* __restrict__ gamma,
                           const float* __restrict__ beta,
                           float* __restrict__ stats) {
    int c = threadIdx.x;
    if (c < DIM) {
        float mu  = stats[c] * (1.0f / N_NODES);
        float var = stats[DIM + c] * (1.0f / N_NODES) - mu * mu;
        float a = gamma[c] * rsqrtf(var + BN_EPS);
        stats[2 * DIM + c] = a;
        stats[3 * DIM + c] = beta[c] - mu * a;
    }
}

// ---------------------------------------------------------------------------
// GEMM2: out = relu(h*a + b) @ W2 + b2, in-place on h (block reads only its rows).
__global__ __launch_bounds__(256) void k_gemm2(float* __restrict__ hio,
                                               const float* __restrict__ stats,
                                               const float* __restrict__ W2,
                                               const float* __restrict__ b2) {
    __shared__ float Bs[BK * DIM];
    __shared__ float As[BM * BK];
    const int t = threadIdx.x;
    const int row0 = blockIdx.x * BM;
    const int trow = (t >> 5) * 4;
    const int tcol = (t & 31) * 4;

    float acc[4][4];
    #pragma unroll
    for (int i = 0; i < 4; ++i)
        #pragma unroll
        for (int j = 0; j < 4; ++j)
            acc[i][j] = b2[tcol + j];

    for (int k0 = 0; k0 < DIM; k0 += BK) {
        const float* wsrc = W2 + k0 * DIM;
        #pragma unroll
        for (int i = t * 4; i < BK * DIM; i += 256 * 4)
            *(float4*)&Bs[i] = *(const float4*)&wsrc[i];
        #pragma unroll
        for (int i = t * 4; i < BM * BK; i += 256 * 4) {
            int r = i >> 6;
            int c = i & (BK - 1);
            int ca = k0 + c;
            size_t g = (size_t)(row0 + r) * DIM + ca;
            float4 hv = *(const float4*)&hio[g];
            float4 av, bv;
            av.x = stats[256 + ca + 0]; av.y = stats[256 + ca + 1];
            av.z = stats[256 + ca + 2]; av.w = stats[256 + ca + 3];
            bv.x = stats[384 + ca + 0]; bv.y = stats[384 + ca + 1];
            bv.z = stats[384 + ca + 2]; bv.w = stats[384 + ca + 3];
            hv.x = fmaxf(fmaf(hv.x, av.x, bv.x), 0.f);
            hv.y = fmaxf(fmaf(hv.y, av.y, bv.y), 0.f);
            hv.z = fmaxf(fmaf(hv.z, av.z, bv.z), 0.f);
            hv.w = fmaxf(fmaf(hv.w, av.w, bv.w), 0.f);
            *(float4*)&As[i] = hv;
        }
        __syncthreads();
        #pragma unroll
        for (int kk = 0; kk < BK; kk += 4) {
            float4 a4[4];
            #pragma unroll
            for (int i = 0; i < 4; ++i)
                a4[i] = *(const float4*)&As[(trow + i) * BK + kk];
            #pragma unroll
            for (int j4 = 0; j4 < 4; ++j4) {
                float4 b = *(const float4*)&Bs[(kk + j4) * DIM + tcol];
                #pragma unroll
                for (int i = 0; i < 4; ++i) {
                    float av = ((const float*)&a4[i])[j4];
                    acc[i][0] = fmaf(av, b.x, acc[i][0]);
                    acc[i][1] = fmaf(av, b.y, acc[i][1]);
                    acc[i][2] = fmaf(av, b.z, acc[i][2]);
                    acc[i][3] = fmaf(av, b.w, acc[i][3]);
                }
            }
        }
        __syncthreads();
    }

    #pragma unroll
    for (int i = 0; i < 4; ++i) {
        float4 v = make_float4(acc[i][0], acc[i][1], acc[i][2], acc[i][3]);
        *(float4*)&hio[(size_t)(row0 + trow + i) * DIM + tcol] = v;
    }
}

// ---------------------------------------------------------------------------
extern "C" void kernel_launch(void* const* d_in, const int* in_sizes, int n_in,
                              void* d_out, int out_size, void* d_ws, size_t ws_size,
                              hipStream_t stream) {
    const float* x     = (const float*)d_in[0];
    const int*   ei    = (const int*)d_in[1];
    const float* W1    = (const float*)d_in[2];
    const float* b1    = (const float*)d_in[3];
    const float* gamma = (const float*)d_in[4];
    const float* beta  = (const float*)d_in[5];
    const float* W2    = (const float*)d_in[6];
    const float* b2    = (const float*)d_in[7];
    const float* eps   = (const float*)d_in[8];
    float* out = (float*)d_out;

    float* agg   = (float*)d_ws;                       // N*128 floats
    float* stats = agg + (size_t)N_NODES * DIM;        // 512 floats (sum, sq, a, b)

    hipMemsetAsync(d_ws, 0,
                   (size_t)N_NODES * DIM * sizeof(float) + 4 * DIM * sizeof(float),
                   stream);
    k_scatter<<<(NEDGE * 128) / 256, 256, 0, stream>>>(x, ei, agg);
    k_gemm1<<<N_NODES / BM, 256, 0, stream>>>(agg, x, eps, W1, b1, out, stats);
    k_finalize<<<1, 128, 0, stream>>>(gamma, beta, stats);
    k_gemm2<<<N_NODES / BM, 256, 0, stream>>>(out, stats, W2, b2);
}

// Round 2
// 402.790 us; speedup vs baseline: 1.3160x; 1.3160x over previous
//
#include <hip/hip_runtime.h>

#define N_NODES 100000
#define DIM     128
#define NEDGE   640000
#define BN_EPS  1e-5f
#define BM      32      // rows per GEMM block
#define BK      64      // k-slice per phase
#define NB_SCAN 98      // ceil(100000/1024)

// ===========================================================================
// CSR build: count -> scan -> fill
// ===========================================================================
__global__ __launch_bounds__(256) void k_count(const int* __restrict__ ei,
                                               int* __restrict__ rowptr) {
    int e = blockIdx.x * 256 + threadIdx.x;
    if (e < NEDGE) atomicAdd(&rowptr[ei[NEDGE + e]], 1);
}

// In-place exclusive scan of 1024-element chunks; block totals to bsum.
__global__ __launch_bounds__(256) void k_scan1(int* __restrict__ rowptr,
                                               int* __restrict__ bsum) {
    __shared__ int tsum[256];
    const int t = threadIdx.x;
    const int base = blockIdx.x * 1024 + t * 4;
    int v[4];
    #pragma unroll
    for (int j = 0; j < 4; ++j)
        v[j] = (base + j < N_NODES) ? rowptr[base + j] : 0;
    int s = v[0] + v[1] + v[2] + v[3];
    tsum[t] = s;
    __syncthreads();
    #pragma unroll
    for (int off = 1; off < 256; off <<= 1) {
        int a = tsum[t];
        int b = (t >= off) ? tsum[t - off] : 0;
        __syncthreads();
        tsum[t] = a + b;
        __syncthreads();
    }
    int run = tsum[t] - s;   // exclusive prefix of this thread within block
    #pragma unroll
    for (int j = 0; j < 4; ++j) {
        int nv = run;
        run += v[j];
        if (base + j < N_NODES) rowptr[base + j] = nv;
    }
    if (t == 255) bsum[blockIdx.x] = tsum[255];
}

__global__ __launch_bounds__(128) void k_scan_mid(int* __restrict__ bsum) {
    __shared__ int sh[128];
    const int t = threadIdx.x;
    int orig = (t < NB_SCAN) ? bsum[t] : 0;
    sh[t] = orig;
    __syncthreads();
    #pragma unroll
    for (int off = 1; off < 128; off <<= 1) {
        int a = sh[t];
        int b = (t >= off) ? sh[t - off] : 0;
        __syncthreads();
        sh[t] = a + b;
        __syncthreads();
    }
    if (t < NB_SCAN) bsum[t] = sh[t] - orig;   // exclusive
}

__global__ __launch_bounds__(256) void k_scan_add(int* __restrict__ rowptr,
                                                  const int* __restrict__ bsum,
                                                  int* __restrict__ cursor) {
    const int t = threadIdx.x;
    const int base = blockIdx.x * 1024 + t * 4;
    const int add = bsum[blockIdx.x];
    #pragma unroll
    for (int j = 0; j < 4; ++j) {
        if (base + j < N_NODES) {
            int r = rowptr[base + j] + add;
            rowptr[base + j] = r;
            cursor[base + j] = r;
        }
    }
    if (blockIdx.x == 0 && t == 0) rowptr[N_NODES] = NEDGE;
}

__global__ __launch_bounds__(256) void k_fill(const int* __restrict__ ei,
                                              int* __restrict__ cursor,
                                              int* __restrict__ srcidx) {
    int e = blockIdx.x * 256 + threadIdx.x;
    if (e < NEDGE) {
        int dst = ei[NEDGE + e];
        int pos = atomicAdd(&cursor[dst], 1);
        srcidx[pos] = ei[e];
    }
}

// ===========================================================================
// Pull aggregation: one wave per node. A[d] = sum_{e->d} x[src] + (1+eps)*x[d]
// ===========================================================================
__global__ __launch_bounds__(256) void k_aggregate(const float* __restrict__ x,
                                                   const int* __restrict__ rowptr,
                                                   const int* __restrict__ srcidx,
                                                   const float* __restrict__ epsp,
                                                   float* __restrict__ A) {
    const int wid  = (blockIdx.x * 256 + threadIdx.x) >> 6;   // node id
    const int lane = threadIdx.x & 63;
    if (wid >= N_NODES) return;
    const float scale = 1.0f + epsp[0];
    const float2* __restrict__ x2 = (const float2*)x;
    const int beg = rowptr[wid];
    const int end = rowptr[wid + 1];
    float2 acc = make_float2(0.f, 0.f);
    for (int p = beg; p < end; ++p) {
        int s = srcidx[p];
        float2 v = x2[(size_t)s * 64 + lane];
        acc.x += v.x;
        acc.y += v.y;
    }
    float2 xd = x2[(size_t)wid * 64 + lane];
    acc.x = fmaf(scale, xd.x, acc.x);
    acc.y = fmaf(scale, xd.y, acc.y);
    ((float2*)A)[(size_t)wid * 64 + lane] = acc;
}

// ===========================================================================
// GEMM1: h = A @ W1 + b1, plus per-column sum/sumsq stats.
// ===========================================================================
__global__ __launch_bounds__(256) void k_gemm1(const float* __restrict__ Ain,
                                               const float* __restrict__ W1,
                                               const float* __restrict__ b1,
                                               float* __restrict__ h,
                                               float* __restrict__ stats) {
    __shared__ float Bs[BK * DIM];   // 32 KB
    __shared__ float As[BM * BK];    // 8 KB
    const int t = threadIdx.x;
    const int row0 = blockIdx.x * BM;
    const int trow = (t >> 5) * 4;
    const int tcol = (t & 31) * 4;

    float acc[4][4];
    #pragma unroll
    for (int i = 0; i < 4; ++i)
        #pragma unroll
        for (int j = 0; j < 4; ++j)
            acc[i][j] = b1[tcol + j];

    for (int k0 = 0; k0 < DIM; k0 += BK) {
        const float* wsrc = W1 + k0 * DIM;
        #pragma unroll
        for (int i = t * 4; i < BK * DIM; i += 256 * 4)
            *(float4*)&Bs[i] = *(const float4*)&wsrc[i];
        #pragma unroll
        for (int i = t * 4; i < BM * BK; i += 256 * 4) {
            int r = i >> 6;
            int c = i & (BK - 1);
            *(float4*)&As[i] = *(const float4*)&Ain[(size_t)(row0 + r) * DIM + k0 + c];
        }
        __syncthreads();
        #pragma unroll
        for (int kk = 0; kk < BK; kk += 4) {
            float4 a4[4];
            #pragma unroll
            for (int i = 0; i < 4; ++i)
                a4[i] = *(const float4*)&As[(trow + i) * BK + kk];
            #pragma unroll
            for (int j4 = 0; j4 < 4; ++j4) {
                float4 b = *(const float4*)&Bs[(kk + j4) * DIM + tcol];
                #pragma unroll
                for (int i = 0; i < 4; ++i) {
                    float av = ((const float*)&a4[i])[j4];
                    acc[i][0] = fmaf(av, b.x, acc[i][0]);
                    acc[i][1] = fmaf(av, b.y, acc[i][1]);
                    acc[i][2] = fmaf(av, b.z, acc[i][2]);
                    acc[i][3] = fmaf(av, b.w, acc[i][3]);
                }
            }
        }
        __syncthreads();
    }

    #pragma unroll
    for (int i = 0; i < 4; ++i) {
        float4 v = make_float4(acc[i][0], acc[i][1], acc[i][2], acc[i][3]);
        *(float4*)&h[(size_t)(row0 + trow + i) * DIM + tcol] = v;
    }

    float s[4], q[4];
    #pragma unroll
    for (int j = 0; j < 4; ++j) {
        s[j] = acc[0][j] + acc[1][j] + acc[2][j] + acc[3][j];
        q[j] = acc[0][j] * acc[0][j] + acc[1][j] * acc[1][j] +
               acc[2][j] * acc[2][j] + acc[3][j] * acc[3][j];
    }
    int rg = t >> 5;
    #pragma unroll
    for (int j = 0; j < 4; ++j) {
        As[rg * 128 + tcol + j] = s[j];
        As[1024 + rg * 128 + tcol + j] = q[j];
    }
    __syncthreads();
    if (t < 128) {
        float ss = 0.f, qq = 0.f;
        #pragma unroll
        for (int g = 0; g < 8; ++g) {
            ss += As[g * 128 + t];
            qq += As[1024 + g * 128 + t];
        }
        atomicAdd(&stats[t], ss);
        atomicAdd(&stats[DIM + t], qq);
    }
}

// ---------------------------------------------------------------------------
__global__ void k_finalize(const float* __restrict__ gamma,
                           const float* __restrict__ beta,
                           float* __restrict__ stats) {
    int c = threadIdx.x;
    if (c < DIM) {
        float mu  = stats[c] * (1.0f / N_NODES);
        float var = stats[DIM + c] * (1.0f / N_NODES) - mu * mu;
        float a = gamma[c] * rsqrtf(var + BN_EPS);
        stats[2 * DIM + c] = a;
        stats[3 * DIM + c] = beta[c] - mu * a;
    }
}

// ---------------------------------------------------------------------------
// GEMM2: out = relu(h*a + b) @ W2 + b2, in-place on h.
__global__ __launch_bounds__(256) void k_gemm2(float* __restrict__ hio,
                                               const float* __restrict__ stats,
                                               const float* __restrict__ W2,
                                               const float* __restrict__ b2) {
    __shared__ float Bs[BK * DIM];
    __shared__ float As[BM * BK];
    const int t = threadIdx.x;
    const int row0 = blockIdx.x * BM;
    const int trow = (t >> 5) * 4;
    const int tcol = (t & 31) * 4;

    float acc[4][4];
    #pragma unroll
    for (int i = 0; i < 4; ++i)
        #pragma unroll
        for (int j = 0; j < 4; ++j)
            acc[i][j] = b2[tcol + j];

    for (int k0 = 0; k0 < DIM; k0 += BK) {
        const float* wsrc = W2 + k0 * DIM;
        #pragma unroll
        for (int i = t * 4; i < BK * DIM; i += 256 * 4)
            *(float4*)&Bs[i] = *(const float4*)&wsrc[i];
        #pragma unroll
        for (int i = t * 4; i < BM * BK; i += 256 * 4) {
            int r = i >> 6;
            int c = i & (BK - 1);
            int ca = k0 + c;
            size_t g = (size_t)(row0 + r) * DIM + ca;
            float4 hv = *(const float4*)&hio[g];
            float4 av, bv;
            av.x = stats[256 + ca + 0]; av.y = stats[256 + ca + 1];
            av.z = stats[256 + ca + 2]; av.w = stats[256 + ca + 3];
            bv.x = stats[384 + ca + 0]; bv.y = stats[384 + ca + 1];
            bv.z = stats[384 + ca + 2]; bv.w = stats[384 + ca + 3];
            hv.x = fmaxf(fmaf(hv.x, av.x, bv.x), 0.f);
            hv.y = fmaxf(fmaf(hv.y, av.y, bv.y), 0.f);
            hv.z = fmaxf(fmaf(hv.z, av.z, bv.z), 0.f);
            hv.w = fmaxf(fmaf(hv.w, av.w, bv.w), 0.f);
            *(float4*)&As[i] = hv;
        }
        __syncthreads();
        #pragma unroll
        for (int kk = 0; kk < BK; kk += 4) {
            float4 a4[4];
            #pragma unroll
            for (int i = 0; i < 4; ++i)
                a4[i] = *(const float4*)&As[(trow + i) * BK + kk];
            #pragma unroll
            for (int j4 = 0; j4 < 4; ++j4) {
                float4 b = *(const float4*)&Bs[(kk + j4) * DIM + tcol];
                #pragma unroll
                for (int i = 0; i < 4; ++i) {
                    float av = ((const float*)&a4[i])[j4];
                    acc[i][0] = fmaf(av, b.x, acc[i][0]);
                    acc[i][1] = fmaf(av, b.y, acc[i][1]);
                    acc[i][2] = fmaf(av, b.z, acc[i][2]);
                    acc[i][3] = fmaf(av, b.w, acc[i][3]);
                }
            }
        }
        __syncthreads();
    }

    #pragma unroll
    for (int i = 0; i < 4; ++i) {
        float4 v = make_float4(acc[i][0], acc[i][1], acc[i][2], acc[i][3]);
        *(float4*)&hio[(size_t)(row0 + trow + i) * DIM + tcol] = v;
    }
}

// ---------------------------------------------------------------------------
extern "C" void kernel_launch(void* const* d_in, const int* in_sizes, int n_in,
                              void* d_out, int out_size, void* d_ws, size_t ws_size,
                              hipStream_t stream) {
    const float* x     = (const float*)d_in[0];
    const int*   ei    = (const int*)d_in[1];
    const float* W1    = (const float*)d_in[2];
    const float* b1    = (const float*)d_in[3];
    const float* gamma = (const float*)d_in[4];
    const float* beta  = (const float*)d_in[5];
    const float* W2    = (const float*)d_in[6];
    const float* b2    = (const float*)d_in[7];
    const float* eps   = (const float*)d_in[8];
    float* out = (float*)d_out;

    // Workspace layout (all 16B aligned)
    float* A      = (float*)d_ws;                           // N*128 floats
    float* stats  = A + (size_t)N_NODES * DIM;              // 512 floats
    int*   rowptr = (int*)(stats + 512);                    // N+1 ints (+pad)
    int*   cursor = rowptr + (N_NODES + 4);                 // N ints
    int*   srcidx = cursor + N_NODES;                       // E ints
    int*   bsum   = srcidx + NEDGE;                         // 128 ints

    // zero: rowptr counts + stats
    hipMemsetAsync(rowptr, 0, (N_NODES + 4) * sizeof(int), stream);
    hipMemsetAsync(stats, 0, 512 * sizeof(float), stream);

    k_count<<<(NEDGE + 255) / 256, 256, 0, stream>>>(ei, rowptr);
    k_scan1<<<NB_SCAN, 256, 0, stream>>>(rowptr, bsum);
    k_scan_mid<<<1, 128, 0, stream>>>(bsum);
    k_scan_add<<<NB_SCAN, 256, 0, stream>>>(rowptr, bsum, cursor);
    k_fill<<<(NEDGE + 255) / 256, 256, 0, stream>>>(ei, cursor, srcidx);
    k_aggregate<<<(N_NODES * 64 + 255) / 256, 256, 0, stream>>>(x, rowptr, srcidx, eps, A);
    k_gemm1<<<N_NODES / BM, 256, 0, stream>>>(A, W1, b1, out, stats);
    k_finalize<<<1, 128, 0, stream>>>(gamma, beta, stats);
    k_gemm2<<<N_NODES / BM, 256, 0, stream>>>(out, stats, W2, b2);
}

// Round 3
// 308.833 us; speedup vs baseline: 1.7164x; 1.3042x over previous
//
#include <hip/hip_runtime.h>

#define N_NODES 100000
#define DIM     128
#define NEDGE   640000
#define BN_EPS  1e-5f
#define NB_SCAN 98      // ceil(100000/1024)
#define BM      64      // rows per GEMM block (4 waves x 16 rows)

typedef __bf16 bf16x8 __attribute__((ext_vector_type(8)));
typedef float  f32x4  __attribute__((ext_vector_type(4)));
typedef unsigned short u16x8 __attribute__((ext_vector_type(8)));

__device__ __forceinline__ unsigned short f2b(float f) {
    unsigned u = __builtin_bit_cast(unsigned, f);
    u += 0x7fffu + ((u >> 16) & 1u);            // RNE
    return (unsigned short)(u >> 16);
}

// ===========================================================================
// CSR build: count -> scan -> fill
// ===========================================================================
__global__ __launch_bounds__(256) void k_count(const int* __restrict__ ei,
                                               int* __restrict__ rowptr) {
    int e = blockIdx.x * 256 + threadIdx.x;
    if (e < NEDGE) atomicAdd(&rowptr[ei[NEDGE + e]], 1);
}

__global__ __launch_bounds__(256) void k_scan1(int* __restrict__ rowptr,
                                               int* __restrict__ bsum) {
    __shared__ int tsum[256];
    const int t = threadIdx.x;
    const int base = blockIdx.x * 1024 + t * 4;
    int v[4];
    #pragma unroll
    for (int j = 0; j < 4; ++j)
        v[j] = (base + j < N_NODES) ? rowptr[base + j] : 0;
    int s = v[0] + v[1] + v[2] + v[3];
    tsum[t] = s;
    __syncthreads();
    #pragma unroll
    for (int off = 1; off < 256; off <<= 1) {
        int a = tsum[t];
        int b = (t >= off) ? tsum[t - off] : 0;
        __syncthreads();
        tsum[t] = a + b;
        __syncthreads();
    }
    int run = tsum[t] - s;
    #pragma unroll
    for (int j = 0; j < 4; ++j) {
        int nv = run;
        run += v[j];
        if (base + j < N_NODES) rowptr[base + j] = nv;
    }
    if (t == 255) bsum[blockIdx.x] = tsum[255];
}

__global__ __launch_bounds__(128) void k_scan_mid(int* __restrict__ bsum) {
    __shared__ int sh[128];
    const int t = threadIdx.x;
    int orig = (t < NB_SCAN) ? bsum[t] : 0;
    sh[t] = orig;
    __syncthreads();
    #pragma unroll
    for (int off = 1; off < 128; off <<= 1) {
        int a = sh[t];
        int b = (t >= off) ? sh[t - off] : 0;
        __syncthreads();
        sh[t] = a + b;
        __syncthreads();
    }
    if (t < NB_SCAN) bsum[t] = sh[t] - orig;
}

__global__ __launch_bounds__(256) void k_scan_add(int* __restrict__ rowptr,
                                                  const int* __restrict__ bsum,
                                                  int* __restrict__ cursor) {
    const int t = threadIdx.x;
    const int base = blockIdx.x * 1024 + t * 4;
    const int add = bsum[blockIdx.x];
    #pragma unroll
    for (int j = 0; j < 4; ++j) {
        if (base + j < N_NODES) {
            int r = rowptr[base + j] + add;
            rowptr[base + j] = r;
            cursor[base + j] = r;
        }
    }
    if (blockIdx.x == 0 && t == 0) rowptr[N_NODES] = NEDGE;
}

__global__ __launch_bounds__(256) void k_fill(const int* __restrict__ ei,
                                              int* __restrict__ cursor,
                                              int* __restrict__ srcidx) {
    int e = blockIdx.x * 256 + threadIdx.x;
    if (e < NEDGE) {
        int dst = ei[NEDGE + e];
        int pos = atomicAdd(&cursor[dst], 1);
        srcidx[pos] = ei[e];
    }
}

// ===========================================================================
// W transpose + bf16 convert: Wt[n][k] = bf16(W[k][n])
// ===========================================================================
__global__ __launch_bounds__(256) void k_convw(const float* __restrict__ W,
                                               unsigned short* __restrict__ Wt) {
    int idx = blockIdx.x * 256 + threadIdx.x;     // 16384 elems
    int k = idx >> 7, n = idx & 127;
    Wt[n * 128 + k] = f2b(W[idx]);
}

// ===========================================================================
// Pull aggregation: A[d] = bf16( sum_{e->d} x[src] + (1+eps)*x[d] )
// One wave per node; lane handles 2 consecutive floats.
// ===========================================================================
__global__ __launch_bounds__(256) void k_aggregate(const float* __restrict__ x,
                                                   const int* __restrict__ rowptr,
                                                   const int* __restrict__ srcidx,
                                                   const float* __restrict__ epsp,
                                                   unsigned short* __restrict__ Ab) {
    const int wid  = (blockIdx.x * 256 + threadIdx.x) >> 6;
    const int lane = threadIdx.x & 63;
    if (wid >= N_NODES) return;
    const float scale = 1.0f + epsp[0];
    const float2* __restrict__ x2 = (const float2*)x;
    const int beg = rowptr[wid];
    const int end = rowptr[wid + 1];
    float2 acc = make_float2(0.f, 0.f);
    int p = beg;
    for (; p + 1 < end; p += 2) {
        int s0 = srcidx[p], s1 = srcidx[p + 1];
        float2 v0 = x2[(size_t)s0 * 64 + lane];
        float2 v1 = x2[(size_t)s1 * 64 + lane];
        acc.x += v0.x + v1.x;
        acc.y += v0.y + v1.y;
    }
    if (p < end) {
        float2 v = x2[(size_t)srcidx[p] * 64 + lane];
        acc.x += v.x;
        acc.y += v.y;
    }
    float2 xd = x2[(size_t)wid * 64 + lane];
    acc.x = fmaf(scale, xd.x, acc.x);
    acc.y = fmaf(scale, xd.y, acc.y);
    ushort2 uv;
    uv.x = f2b(acc.x);
    uv.y = f2b(acc.y);
    ((ushort2*)Ab)[(size_t)wid * 64 + lane] = uv;
}

// ===========================================================================
// GEMM1 (MFMA bf16): h = A @ W1 + b1 (h bf16, in-place over A) + BN stats.
// Block: 4 waves x 16 rows; each wave: 8 col-tiles of 16x16, K=128 in 4 steps.
// ===========================================================================
__global__ __launch_bounds__(256) void k_gemm1(unsigned short* __restrict__ Ab,
                                               const unsigned short* __restrict__ Wt,
                                               const float* __restrict__ b1,
                                               float* __restrict__ stats) {
    __shared__ __align__(16) unsigned short ws[128 * 136];  // 34816 B, Wt then out-staging
    __shared__ float sl[256];
    const int t = threadIdx.x;
    const int w = t >> 6;
    const int lane = t & 63;
    const int n15 = lane & 15;
    const int quad = lane >> 4;

    {   // stage Wt (pad rows to 136 bf16 -> 2-way bank aliasing, free)
        const int row = t >> 1, half = t & 1;
        const float4* src = (const float4*)(Wt + row * 128 + half * 64);
        float4* dst = (float4*)(&ws[row * 136 + half * 64]);
        #pragma unroll
        for (int i = 0; i < 8; ++i) dst[i] = src[i];
    }
    sl[t] = 0.f;
    __syncthreads();

    const int row0 = blockIdx.x * BM + w * 16;
    const bool valid = (row0 < N_NODES);

    f32x4 acc[8] = {};
    if (valid) {
        const size_t abase = (size_t)(row0 + n15) * 128;
        #pragma unroll
        for (int ks = 0; ks < 4; ++ks) {
            int4 araw = *(const int4*)(Ab + abase + ks * 32 + quad * 8);
            bf16x8 af = __builtin_bit_cast(bf16x8, araw);
            #pragma unroll
            for (int c = 0; c < 8; ++c) {
                int4 braw = *(const int4*)(&ws[(c * 16 + n15) * 136 + ks * 32 + quad * 8]);
                bf16x8 bf = __builtin_bit_cast(bf16x8, braw);
                acc[c] = __builtin_amdgcn_mfma_f32_16x16x32_bf16(af, bf, acc[c], 0, 0, 0);
            }
        }
        // bias + per-column stats (this wave's 16 rows)
        #pragma unroll
        for (int c = 0; c < 8; ++c) {
            float bias = b1[c * 16 + n15];
            float s = 0.f, q = 0.f;
            #pragma unroll
            for (int r = 0; r < 4; ++r) {
                float v = acc[c][r] + bias;
                acc[c][r] = v;
                s += v; q += v * v;
            }
            s += __shfl_down(s, 32); q += __shfl_down(q, 32);
            s += __shfl_down(s, 16); q += __shfl_down(q, 16);
            if (quad == 0) {
                atomicAdd(&sl[c * 16 + n15], s);
                atomicAdd(&sl[128 + c * 16 + n15], q);
            }
        }
    }
    __syncthreads();   // Wt reads + sl atomics complete
    atomicAdd(&stats[t], sl[t]);   // stats[0:128]=sum, [128:256]=sumsq

    // stage h tile (bf16) through LDS for coalesced stores
    unsigned short* outLds = &ws[w * 2048];
    if (valid) {
        #pragma unroll
        for (int c = 0; c < 8; ++c)
            #pragma unroll
            for (int r = 0; r < 4; ++r)
                outLds[(quad * 4 + r) * 128 + c * 16 + n15] = f2b(acc[c][r]);
    }
    __syncthreads();
    if (valid) {
        const size_t gbase = (size_t)row0 * 128;
        #pragma unroll
        for (int p = 0; p < 4; ++p) {
            int off = p * 512 + lane * 8;
            *(int4*)(Ab + gbase + off) = *(const int4*)(outLds + off);
        }
    }
}

// ---------------------------------------------------------------------------
__global__ void k_finalize(const float* __restrict__ gamma,
                           const float* __restrict__ beta,
                           float* __restrict__ stats) {
    int c = threadIdx.x;
    if (c < DIM) {
        float mu  = stats[c] * (1.0f / N_NODES);
        float var = stats[DIM + c] * (1.0f / N_NODES) - mu * mu;
        float a = gamma[c] * rsqrtf(var + BN_EPS);
        stats[2 * DIM + c] = a;
        stats[3 * DIM + c] = beta[c] - mu * a;
    }
}

// ===========================================================================
// GEMM2 (MFMA bf16): out = relu(h*a + b) @ W2 + b2, fp32 out.
// BN affine + ReLU fused into the A-fragment load.
// ===========================================================================
__global__ __launch_bounds__(256) void k_gemm2(const unsigned short* __restrict__ hb,
                                               const unsigned short* __restrict__ Wt2,
                                               const float* __restrict__ stats,
                                               const float* __restrict__ b2,
                                               float* __restrict__ out) {
    __shared__ __align__(16) unsigned short ws[128 * 136];  // Wt2, reused as fp32 out-staging
    const int t = threadIdx.x;
    const int w = t >> 6;
    const int lane = t & 63;
    const int n15 = lane & 15;
    const int quad = lane >> 4;

    {
        const int row = t >> 1, half = t & 1;
        const float4* src = (const float4*)(Wt2 + row * 128 + half * 64);
        float4* dst = (float4*)(&ws[row * 136 + half * 64]);
        #pragma unroll
        for (int i = 0; i < 8; ++i) dst[i] = src[i];
    }
    __syncthreads();

    const int row0 = blockIdx.x * BM + w * 16;
    const bool valid = (row0 < N_NODES);

    f32x4 acc[8] = {};
    if (valid) {
        const size_t abase = (size_t)(row0 + n15) * 128;
        #pragma unroll
        for (int ks = 0; ks < 4; ++ks) {
            const int kbase = ks * 32 + quad * 8;
            int4 araw = *(const int4*)(hb + abase + kbase);
            u16x8 ar = __builtin_bit_cast(u16x8, araw);
            float ak[8], bk[8];
            *(float4*)(ak)     = *(const float4*)(stats + 256 + kbase);
            *(float4*)(ak + 4) = *(const float4*)(stats + 256 + kbase + 4);
            *(float4*)(bk)     = *(const float4*)(stats + 384 + kbase);
            *(float4*)(bk + 4) = *(const float4*)(stats + 384 + kbase + 4);
            u16x8 pr;
            #pragma unroll
            for (int j = 0; j < 8; ++j) {
                float f = __builtin_bit_cast(float, ((unsigned)ar[j]) << 16);
                f = fmaxf(fmaf(f, ak[j], bk[j]), 0.f);
                unsigned uu = __builtin_bit_cast(unsigned, f);
                uu += 0x7fffu + ((uu >> 16) & 1u);
                pr[j] = (unsigned short)(uu >> 16);
            }
            bf16x8 af = __builtin_bit_cast(bf16x8, pr);
            #pragma unroll
            for (int c = 0; c < 8; ++c) {
                int4 braw = *(const int4*)(&ws[(c * 16 + n15) * 136 + kbase]);
                bf16x8 bf = __builtin_bit_cast(bf16x8, braw);
                acc[c] = __builtin_amdgcn_mfma_f32_16x16x32_bf16(af, bf, acc[c], 0, 0, 0);
            }
        }
    }
    __syncthreads();   // done with Wt2 region
    float* outLds = (float*)ws + w * 2048;   // 8 KB per wave
    if (valid) {
        #pragma unroll
        for (int c = 0; c < 8; ++c) {
            float bias = b2[c * 16 + n15];
            #pragma unroll
            for (int r = 0; r < 4; ++r)
                outLds[(quad * 4 + r) * 128 + c * 16 + n15] = acc[c][r] + bias;
        }
    }
    __syncthreads();
    if (valid) {
        const size_t gbase = (size_t)row0 * 128;
        #pragma unroll
        for (int p = 0; p < 8; ++p) {
            int off = p * 256 + lane * 4;
            *(float4*)(out + gbase + off) = *(const float4*)(outLds + off);
        }
    }
}

// ---------------------------------------------------------------------------
extern "C" void kernel_launch(void* const* d_in, const int* in_sizes, int n_in,
                              void* d_out, int out_size, void* d_ws, size_t ws_size,
                              hipStream_t stream) {
    const float* x     = (const float*)d_in[0];
    const int*   ei    = (const int*)d_in[1];
    const float* W1    = (const float*)d_in[2];
    const float* b1    = (const float*)d_in[3];
    const float* gamma = (const float*)d_in[4];
    const float* beta  = (const float*)d_in[5];
    const float* W2    = (const float*)d_in[6];
    const float* b2    = (const float*)d_in[7];
    const float* eps   = (const float*)d_in[8];
    float* out = (float*)d_out;

    // Workspace layout (16B-aligned sections)
    unsigned short* Ab  = (unsigned short*)d_ws;            // N*128 bf16 (A, then h in-place)
    float* stats        = (float*)(Ab + (size_t)N_NODES * DIM);  // 512 f
    unsigned short* Wt1 = (unsigned short*)(stats + 512);   // 16384 bf16
    unsigned short* Wt2 = Wt1 + 16384;                      // 16384 bf16
    int* rowptr         = (int*)(Wt2 + 16384);              // N+1 (+pad)
    int* cursor         = rowptr + (N_NODES + 4);           // N
    int* srcidx         = cursor + N_NODES;                 // E
    int* bsum           = srcidx + NEDGE;                   // 128

    hipMemsetAsync(rowptr, 0, (N_NODES + 4) * sizeof(int), stream);
    hipMemsetAsync(stats, 0, 512 * sizeof(float), stream);

    k_convw<<<64, 256, 0, stream>>>(W1, Wt1);
    k_convw<<<64, 256, 0, stream>>>(W2, Wt2);
    k_count<<<(NEDGE + 255) / 256, 256, 0, stream>>>(ei, rowptr);
    k_scan1<<<NB_SCAN, 256, 0, stream>>>(rowptr, bsum);
    k_scan_mid<<<1, 128, 0, stream>>>(bsum);
    k_scan_add<<<NB_SCAN, 256, 0, stream>>>(rowptr, bsum, cursor);
    k_fill<<<(NEDGE + 255) / 256, 256, 0, stream>>>(ei, cursor, srcidx);
    k_aggregate<<<(N_NODES * 64) / 256, 256, 0, stream>>>(x, rowptr, srcidx, eps, Ab);
    k_gemm1<<<(N_NODES + BM - 1) / BM, 256, 0, stream>>>(Ab, Wt1, b1, stats);
    k_finalize<<<1, 128, 0, stream>>>(gamma, beta, stats);
    k_gemm2<<<(N_NODES + BM - 1) / BM, 256, 0, stream>>>(Ab, Wt2, stats, b2, out);
}

// Round 4
// 294.801 us; speedup vs baseline: 1.7981x; 1.0476x over previous
//
#include <hip/hip_runtime.h>

#define N_NODES 100000
#define DIM     128
#define NEDGE   640000
#define BN_EPS  1e-5f
#define NB_SCAN 98      // ceil(100000/1024)
#define BM      64      // rows per GEMM block (4 waves x 16 rows)

// k_prep block ranges
#define PB_X    6250    // 12.8M elems / (256 thr * 8)
#define PB_W    64      // 16384 / 256
#define PB_CNT  2500    // 640000 / 256

typedef __bf16 bf16x8 __attribute__((ext_vector_type(8)));
typedef float  f32x4  __attribute__((ext_vector_type(4)));
typedef unsigned short u16x8 __attribute__((ext_vector_type(8)));

__device__ __forceinline__ unsigned short f2b(float f) {
    unsigned u = __builtin_bit_cast(unsigned, f);
    u += 0x7fffu + ((u >> 16) & 1u);            // RNE
    return (unsigned short)(u >> 16);
}
__device__ __forceinline__ float b2f(unsigned short b) {
    return __builtin_bit_cast(float, ((unsigned)b) << 16);
}

// ===========================================================================
// Fused prep: x->bf16, W1/W2 transpose->bf16, degree count.
// ===========================================================================
__global__ __launch_bounds__(256) void k_prep(const float* __restrict__ x,
                                              const float* __restrict__ W1,
                                              const float* __restrict__ W2,
                                              const int* __restrict__ ei,
                                              unsigned short* __restrict__ xb,
                                              unsigned short* __restrict__ Wt1,
                                              unsigned short* __restrict__ Wt2,
                                              int* __restrict__ rowptr) {
    const int b = blockIdx.x;
    const int t = threadIdx.x;
    if (b < PB_X) {
        size_t base = ((size_t)b * 256 + t) * 8;
        float4 v0 = *(const float4*)(x + base);
        float4 v1 = *(const float4*)(x + base + 4);
        u16x8 o;
        o[0] = f2b(v0.x); o[1] = f2b(v0.y); o[2] = f2b(v0.z); o[3] = f2b(v0.w);
        o[4] = f2b(v1.x); o[5] = f2b(v1.y); o[6] = f2b(v1.z); o[7] = f2b(v1.w);
        *(u16x8*)(xb + base) = o;
    } else if (b < PB_X + PB_W) {
        int idx = (b - PB_X) * 256 + t;
        int k = idx >> 7, n = idx & 127;
        Wt1[n * 128 + k] = f2b(W1[idx]);
    } else if (b < PB_X + 2 * PB_W) {
        int idx = (b - PB_X - PB_W) * 256 + t;
        int k = idx >> 7, n = idx & 127;
        Wt2[n * 128 + k] = f2b(W2[idx]);
    } else {
        int e = (b - PB_X - 2 * PB_W) * 256 + t;
        if (e < NEDGE) atomicAdd(&rowptr[ei[NEDGE + e]], 1);
    }
}

// ===========================================================================
// CSR scan + fill
// ===========================================================================
__global__ __launch_bounds__(256) void k_scan1(int* __restrict__ rowptr,
                                               int* __restrict__ bsum) {
    __shared__ int tsum[256];
    const int t = threadIdx.x;
    const int base = blockIdx.x * 1024 + t * 4;
    int v[4];
    #pragma unroll
    for (int j = 0; j < 4; ++j)
        v[j] = (base + j < N_NODES) ? rowptr[base + j] : 0;
    int s = v[0] + v[1] + v[2] + v[3];
    tsum[t] = s;
    __syncthreads();
    #pragma unroll
    for (int off = 1; off < 256; off <<= 1) {
        int a = tsum[t];
        int b = (t >= off) ? tsum[t - off] : 0;
        __syncthreads();
        tsum[t] = a + b;
        __syncthreads();
    }
    int run = tsum[t] - s;
    #pragma unroll
    for (int j = 0; j < 4; ++j) {
        int nv = run;
        run += v[j];
        if (base + j < N_NODES) rowptr[base + j] = nv;
    }
    if (t == 255) bsum[blockIdx.x] = tsum[255];
}

__global__ __launch_bounds__(128) void k_scan_mid(int* __restrict__ bsum) {
    __shared__ int sh[128];
    const int t = threadIdx.x;
    int orig = (t < NB_SCAN) ? bsum[t] : 0;
    sh[t] = orig;
    __syncthreads();
    #pragma unroll
    for (int off = 1; off < 128; off <<= 1) {
        int a = sh[t];
        int b = (t >= off) ? sh[t - off] : 0;
        __syncthreads();
        sh[t] = a + b;
        __syncthreads();
    }
    if (t < NB_SCAN) bsum[t] = sh[t] - orig;
}

__global__ __launch_bounds__(256) void k_scan_add(int* __restrict__ rowptr,
                                                  const int* __restrict__ bsum,
                                                  int* __restrict__ cursor) {
    const int t = threadIdx.x;
    const int base = blockIdx.x * 1024 + t * 4;
    const int add = bsum[blockIdx.x];
    #pragma unroll
    for (int j = 0; j < 4; ++j) {
        if (base + j < N_NODES) {
            int r = rowptr[base + j] + add;
            rowptr[base + j] = r;
            cursor[base + j] = r;
        }
    }
    if (blockIdx.x == 0 && t == 0) rowptr[N_NODES] = NEDGE;
}

__global__ __launch_bounds__(256) void k_fill(const int* __restrict__ ei,
                                              int* __restrict__ cursor,
                                              int* __restrict__ srcidx) {
    int e = blockIdx.x * 256 + threadIdx.x;
    if (e < NEDGE) {
        int dst = ei[NEDGE + e];
        int pos = atomicAdd(&cursor[dst], 1);
        srcidx[pos] = ei[e];
    }
}

// ===========================================================================
// Pull aggregation (bf16 gather, 4 edges per load instruction).
// One wave per node; group g=lane>>4 handles edge p+g; lane covers 8 cols.
// ===========================================================================
__global__ __launch_bounds__(256) void k_aggregate(const unsigned short* __restrict__ xb,
                                                   const int* __restrict__ rowptr,
                                                   const int* __restrict__ srcidx,
                                                   const float* __restrict__ epsp,
                                                   unsigned short* __restrict__ Ab) {
    const int wid  = (blockIdx.x * 256 + threadIdx.x) >> 6;
    const int lane = threadIdx.x & 63;
    if (wid >= N_NODES) return;
    const int g = lane >> 4;        // edge group 0..3
    const int c = (lane & 15) * 8;  // col offset
    const float scale = 1.0f + epsp[0];
    const int beg = rowptr[wid];
    const int end = rowptr[wid + 1];

    float acc[8] = {0.f, 0.f, 0.f, 0.f, 0.f, 0.f, 0.f, 0.f};
    for (int p = beg; p < end; p += 4) {
        int e = p + g;
        if (e < end) {
            int s = srcidx[e];
            u16x8 v = *(const u16x8*)(xb + (size_t)s * 128 + c);
            #pragma unroll
            for (int j = 0; j < 8; ++j) acc[j] += b2f(v[j]);
        }
    }
    if (g == 0) {   // self term lives in group 0, survives the reduction
        u16x8 v = *(const u16x8*)(xb + (size_t)wid * 128 + c);
        #pragma unroll
        for (int j = 0; j < 8; ++j) acc[j] = fmaf(scale, b2f(v[j]), acc[j]);
    }
    #pragma unroll
    for (int j = 0; j < 8; ++j) acc[j] += __shfl_down(acc[j], 32);
    #pragma unroll
    for (int j = 0; j < 8; ++j) acc[j] += __shfl_down(acc[j], 16);
    if (lane < 16) {
        u16x8 o;
        #pragma unroll
        for (int j = 0; j < 8; ++j) o[j] = f2b(acc[j]);
        *(u16x8*)(Ab + (size_t)wid * 128 + c) = o;
    }
}

// ===========================================================================
// GEMM1 (MFMA bf16): h = A @ W1 + b1 (bf16, in-place over A) + BN stats.
// ===========================================================================
__global__ __launch_bounds__(256) void k_gemm1(unsigned short* __restrict__ Ab,
                                               const unsigned short* __restrict__ Wt,
                                               const float* __restrict__ b1,
                                               float* __restrict__ stats) {
    __shared__ __align__(16) unsigned short ws[128 * 136];
    __shared__ float sl[256];
    const int t = threadIdx.x;
    const int w = t >> 6;
    const int lane = t & 63;
    const int n15 = lane & 15;
    const int quad = lane >> 4;

    {
        const int row = t >> 1, half = t & 1;
        const float4* src = (const float4*)(Wt + row * 128 + half * 64);
        float4* dst = (float4*)(&ws[row * 136 + half * 64]);
        #pragma unroll
        for (int i = 0; i < 8; ++i) dst[i] = src[i];
    }
    sl[t] = 0.f;
    __syncthreads();

    const int row0 = blockIdx.x * BM + w * 16;
    const bool valid = (row0 < N_NODES);

    f32x4 acc[8] = {};
    if (valid) {
        const size_t abase = (size_t)(row0 + n15) * 128;
        #pragma unroll
        for (int ks = 0; ks < 4; ++ks) {
            int4 araw = *(const int4*)(Ab + abase + ks * 32 + quad * 8);
            bf16x8 af = __builtin_bit_cast(bf16x8, araw);
            #pragma unroll
            for (int c = 0; c < 8; ++c) {
                int4 braw = *(const int4*)(&ws[(c * 16 + n15) * 136 + ks * 32 + quad * 8]);
                bf16x8 bf = __builtin_bit_cast(bf16x8, braw);
                acc[c] = __builtin_amdgcn_mfma_f32_16x16x32_bf16(af, bf, acc[c], 0, 0, 0);
            }
        }
        #pragma unroll
        for (int c = 0; c < 8; ++c) {
            float bias = b1[c * 16 + n15];
            float s = 0.f, q = 0.f;
            #pragma unroll
            for (int r = 0; r < 4; ++r) {
                float v = acc[c][r] + bias;
                acc[c][r] = v;
                s += v; q += v * v;
            }
            s += __shfl_down(s, 32); q += __shfl_down(q, 32);
            s += __shfl_down(s, 16); q += __shfl_down(q, 16);
            if (quad == 0) {
                atomicAdd(&sl[c * 16 + n15], s);
                atomicAdd(&sl[128 + c * 16 + n15], q);
            }
        }
    }
    __syncthreads();
    atomicAdd(&stats[t], sl[t]);

    unsigned short* outLds = &ws[w * 2048];
    if (valid) {
        #pragma unroll
        for (int c = 0; c < 8; ++c)
            #pragma unroll
            for (int r = 0; r < 4; ++r)
                outLds[(quad * 4 + r) * 128 + c * 16 + n15] = f2b(acc[c][r]);
    }
    __syncthreads();
    if (valid) {
        const size_t gbase = (size_t)row0 * 128;
        #pragma unroll
        for (int p = 0; p < 4; ++p) {
            int off = p * 512 + lane * 8;
            *(int4*)(Ab + gbase + off) = *(const int4*)(outLds + off);
        }
    }
}

// ---------------------------------------------------------------------------
__global__ void k_finalize(const float* __restrict__ gamma,
                           const float* __restrict__ beta,
                           float* __restrict__ stats) {
    int c = threadIdx.x;
    if (c < DIM) {
        float mu  = stats[c] * (1.0f / N_NODES);
        float var = stats[DIM + c] * (1.0f / N_NODES) - mu * mu;
        float a = gamma[c] * rsqrtf(var + BN_EPS);
        stats[2 * DIM + c] = a;
        stats[3 * DIM + c] = beta[c] - mu * a;
    }
}

// ===========================================================================
// GEMM2 (MFMA bf16): out = relu(h*a + b) @ W2 + b2, fp32 out.
// ===========================================================================
__global__ __launch_bounds__(256) void k_gemm2(const unsigned short* __restrict__ hb,
                                               const unsigned short* __restrict__ Wt2,
                                               const float* __restrict__ stats,
                                               const float* __restrict__ b2,
                                               float* __restrict__ out) {
    __shared__ __align__(16) unsigned short ws[128 * 136];
    const int t = threadIdx.x;
    const int w = t >> 6;
    const int lane = t & 63;
    const int n15 = lane & 15;
    const int quad = lane >> 4;

    {
        const int row = t >> 1, half = t & 1;
        const float4* src = (const float4*)(Wt2 + row * 128 + half * 64);
        float4* dst = (float4*)(&ws[row * 136 + half * 64]);
        #pragma unroll
        for (int i = 0; i < 8; ++i) dst[i] = src[i];
    }
    __syncthreads();

    const int row0 = blockIdx.x * BM + w * 16;
    const bool valid = (row0 < N_NODES);

    f32x4 acc[8] = {};
    if (valid) {
        const size_t abase = (size_t)(row0 + n15) * 128;
        #pragma unroll
        for (int ks = 0; ks < 4; ++ks) {
            const int kbase = ks * 32 + quad * 8;
            int4 araw = *(const int4*)(hb + abase + kbase);
            u16x8 ar = __builtin_bit_cast(u16x8, araw);
            float ak[8], bk[8];
            *(float4*)(ak)     = *(const float4*)(stats + 256 + kbase);
            *(float4*)(ak + 4) = *(const float4*)(stats + 256 + kbase + 4);
            *(float4*)(bk)     = *(const float4*)(stats + 384 + kbase);
            *(float4*)(bk + 4) = *(const float4*)(stats + 384 + kbase + 4);
            u16x8 pr;
            #pragma unroll
            for (int j = 0; j < 8; ++j) {
                float f = b2f(ar[j]);
                f = fmaxf(fmaf(f, ak[j], bk[j]), 0.f);
                pr[j] = f2b(f);
            }
            bf16x8 af = __builtin_bit_cast(bf16x8, pr);
            #pragma unroll
            for (int c = 0; c < 8; ++c) {
                int4 braw = *(const int4*)(&ws[(c * 16 + n15) * 136 + kbase]);
                bf16x8 bf = __builtin_bit_cast(bf16x8, braw);
                acc[c] = __builtin_amdgcn_mfma_f32_16x16x32_bf16(af, bf, acc[c], 0, 0, 0);
            }
        }
    }
    __syncthreads();
    float* outLds = (float*)ws + w * 2048;
    if (valid) {
        #pragma unroll
        for (int c = 0; c < 8; ++c) {
            float bias = b2[c * 16 + n15];
            #pragma unroll
            for (int r = 0; r < 4; ++r)
                outLds[(quad * 4 + r) * 128 + c * 16 + n15] = acc[c][r] + bias;
        }
    }
    __syncthreads();
    if (valid) {
        const size_t gbase = (size_t)row0 * 128;
        #pragma unroll
        for (int p = 0; p < 8; ++p) {
            int off = p * 256 + lane * 4;
            *(float4*)(out + gbase + off) = *(const float4*)(outLds + off);
        }
    }
}

// ---------------------------------------------------------------------------
extern "C" void kernel_launch(void* const* d_in, const int* in_sizes, int n_in,
                              void* d_out, int out_size, void* d_ws, size_t ws_size,
                              hipStream_t stream) {
    const float* x     = (const float*)d_in[0];
    const int*   ei    = (const int*)d_in[1];
    const float* W1    = (const float*)d_in[2];
    const float* b1    = (const float*)d_in[3];
    const float* gamma = (const float*)d_in[4];
    const float* beta  = (const float*)d_in[5];
    const float* W2    = (const float*)d_in[6];
    const float* b2    = (const float*)d_in[7];
    const float* eps   = (const float*)d_in[8];
    float* out = (float*)d_out;

    // Workspace layout: stats and rowptr adjacent so ONE memset zeroes both.
    float* stats        = (float*)d_ws;                     // 512 f
    int* rowptr         = (int*)(stats + 512);              // N+4 ints
    unsigned short* Ab  = (unsigned short*)(rowptr + N_NODES + 4);  // N*128 bf16
    unsigned short* xb  = Ab + (size_t)N_NODES * DIM;       // N*128 bf16
    unsigned short* Wt1 = xb + (size_t)N_NODES * DIM;       // 16384 bf16
    unsigned short* Wt2 = Wt1 + 16384;                      // 16384 bf16
    int* cursor         = (int*)(Wt2 + 16384);              // N
    int* srcidx         = cursor + N_NODES;                 // E
    int* bsum           = srcidx + NEDGE;                   // 128

    hipMemsetAsync(stats, 0, 512 * sizeof(float) + (N_NODES + 4) * sizeof(int), stream);

    k_prep<<<PB_X + 2 * PB_W + PB_CNT, 256, 0, stream>>>(x, W1, W2, ei, xb, Wt1, Wt2, rowptr);
    k_scan1<<<NB_SCAN, 256, 0, stream>>>(rowptr, bsum);
    k_scan_mid<<<1, 128, 0, stream>>>(bsum);
    k_scan_add<<<NB_SCAN, 256, 0, stream>>>(rowptr, bsum, cursor);
    k_fill<<<(NEDGE + 255) / 256, 256, 0, stream>>>(ei, cursor, srcidx);
    k_aggregate<<<(N_NODES * 64) / 256, 256, 0, stream>>>(xb, rowptr, srcidx, eps, Ab);
    k_gemm1<<<(N_NODES + BM - 1) / BM, 256, 0, stream>>>(Ab, Wt1, b1, stats);
    k_finalize<<<1, 128, 0, stream>>>(gamma, beta, stats);
    k_gemm2<<<(N_NODES + BM - 1) / BM, 256, 0, stream>>>(Ab, Wt2, stats, b2, out);
}